// Round 2
// baseline (115.419 us; speedup 1.0000x reference)
//
#include <hip/hip_runtime.h>
#include <float.h>
#include <math.h>

#define NB 8192      // batch
#define NC 128       // classes
#define NT 64        // time steps
#define ACE_EPS 1e-5f
#define GRID (NB / 4)

// workspace layout:
//   [0, NB*4)            prefix[NB]  (int)
//   [NB*4, NB*4+8)       acc         (unsigned long long, fixed-point 2^32 loss sum)
//   [NB*4+8, NB*4+12)    ticket      (unsigned int)

// ---------------------------------------------------------------------------
// 1) exclusive prefix sum of target_lengths + zero the accumulator/ticket.
//    256 threads, int4 loads (8192 ints), shuffle scan. ~2 us.
// ---------------------------------------------------------------------------
__global__ __launch_bounds__(256) void prefix_kernel(
    const int* __restrict__ lens, int* __restrict__ prefix,
    unsigned long long* __restrict__ acc, unsigned int* __restrict__ ticket) {
  if (threadIdx.x == 0) { *acc = 0ull; *ticket = 0u; }
  const int tid = threadIdx.x;
  const int lane = tid & 63;
  const int wid = tid >> 6;

  int4 v[8];
  const int4* l4 = (const int4*)lens + tid * 8;   // 32 ints per thread
#pragma unroll
  for (int i = 0; i < 8; ++i) v[i] = l4[i];
  int s = 0;
#pragma unroll
  for (int i = 0; i < 8; ++i) s += v[i].x + v[i].y + v[i].z + v[i].w;

  // inclusive shuffle scan of per-thread sums within each wave
  int scan = s;
#pragma unroll
  for (int off = 1; off < 64; off <<= 1) {
    int t = __shfl_up(scan, off, 64);
    if (lane >= off) scan += t;
  }
  __shared__ int wsum[4];
  if (lane == 63) wsum[wid] = scan;
  __syncthreads();
  int wbase = 0;
  for (int w = 0; w < wid; ++w) wbase += wsum[w];

  int run = wbase + scan - s;   // exclusive prefix of this thread's 32-chunk
  int4 o[8];
#pragma unroll
  for (int i = 0; i < 8; ++i) {
    const int a = run;
    const int b2 = a + v[i].x;
    const int c2 = b2 + v[i].y;
    const int d2 = c2 + v[i].z;
    o[i] = make_int4(a, b2, c2, d2);
    run = d2 + v[i].w;
  }
  int4* p4 = (int4*)prefix + tid * 8;
#pragma unroll
  for (int i = 0; i < 8; ++i) p4[i] = o[i];
}

// ---------------------------------------------------------------------------
// 2) fused per-sample ACE loss + deterministic global mean.
//    One wave per sample, 4 samples per 256-thread block.
//    Lane mapping: tg = lane&15 covers t = 4*tg..4*tg+3 (float4 load),
//                  crow = lane>>4 covers c = 4*cc + crow.
//    Wave reads float4 at flat index 64*cc + lane: 1 KiB contiguous / iter.
//    All histogram state is per-wave (own LDS rows) -> no __syncthreads in
//    the hot path; waves run decoupled.
//    Mean fused via fixed-point (x 2^32) u64 atomic: order-independent ->
//    bit-deterministic. Last block (ticket) writes d_out.
// ---------------------------------------------------------------------------
__global__ __launch_bounds__(256, 8) void ace_kernel(
    const float* __restrict__ x, const int* __restrict__ y,
    const int* __restrict__ lens, const int* __restrict__ prefix,
    unsigned long long* __restrict__ acc, unsigned int* __restrict__ ticket,
    float* __restrict__ out) {
  const int wave = threadIdx.x >> 6;
  const int lane = threadIdx.x & 63;
  const int b = blockIdx.x * 4 + wave;
  const int tg = lane & 15;
  const int crow = lane >> 4;

  __shared__ int nk[4][NC];
  __shared__ int yk[4][NC];
  __shared__ float wloss[4];
  // per-wave rows only -> wave-internal ordering suffices, no block sync
  nk[wave][lane] = 0; nk[wave][lane + 64] = 0;
  yk[wave][lane] = 0; yk[wave][lane + 64] = 0;

  // ---- target histogram first: its few loads hide under the x stream ----
  const int len = lens[b];
  const int start = prefix[b];
  for (int i = lane; i < len; i += 64) atomicAdd(&yk[wave][y[start + i]], 1);

  // ---- streaming argmax over C for each t ----
  const float4* xv = (const float4*)(x + (size_t)b * (NC * NT));
  float mv[4];
  int am[4];
#pragma unroll
  for (int j = 0; j < 4; ++j) { mv[j] = -FLT_MAX; am[j] = 0; }

#pragma unroll 8
  for (int cc = 0; cc < 32; ++cc) {
    const int c = cc * 4 + crow;
    float4 v = xv[cc * 64 + lane];
    float vv[4] = {v.x, v.y, v.z, v.w};
#pragma unroll
    for (int j = 0; j < 4; ++j) {
      if (vv[j] > mv[j]) { mv[j] = vv[j]; am[j] = c; }   // strict > : first max
    }
  }

  // combine across the 4 lanes (crow dim) sharing one t-group; min idx on tie
#pragma unroll
  for (int j = 0; j < 4; ++j) {
#pragma unroll
    for (int off = 16; off < 64; off <<= 1) {
      float om = __shfl_xor(mv[j], off, 64);
      int oa = __shfl_xor(am[j], off, 64);
      if (om > mv[j] || (om == mv[j] && oa < am[j])) { mv[j] = om; am[j] = oa; }
    }
  }

  // lane records argmax for t = 4*tg + crow (static-index select chain)
  int my_am = am[0];
  if (crow == 1) my_am = am[1];
  if (crow == 2) my_am = am[2];
  if (crow == 3) my_am = am[3];
  atomicAdd(&nk[wave][my_am], 1);

  // ---- per-sample masked loss (classes lane, lane+64) ----
  const int yk0 = yk[wave][lane], yk1 = yk[wave][lane + 64];
  const int nk0 = yk0 ? nk[wave][lane] : 0;
  const int nk1 = yk1 ? nk[wave][lane + 64] : 0;
  int ns = nk0 + nk1;
  int ys = yk0 + yk1;
#pragma unroll
  for (int off = 1; off < 64; off <<= 1) {
    ns += __shfl_xor(ns, off, 64);
    ys += __shfl_xor(ys, off, 64);
  }
  const float inv_ns = (ns > 0) ? (1.0f / (float)ns) : 0.0f;
  const float inv_ys = (ys > 0) ? (1.0f / (float)ys) : 0.0f;
  float a = 0.0f;
  if (yk0) {
    float np = (ns == 0) ? ACE_EPS : fmaxf((float)nk0 * inv_ns, ACE_EPS);
    a -= np * logf((float)yk0 * inv_ys);
  }
  if (yk1) {
    float np = (ns == 0) ? ACE_EPS : fmaxf((float)nk1 * inv_ns, ACE_EPS);
    a -= np * logf((float)yk1 * inv_ys);
  }
#pragma unroll
  for (int off = 1; off < 64; off <<= 1) a += __shfl_xor(a, off, 64);
  if (lane == 0) wloss[wave] = a;

  // ---- deterministic fused mean ----
  __syncthreads();
  if (threadIdx.x == 0) {
    // fixed order within block; integer atomic across blocks: deterministic
    double bl = (double)wloss[0] + (double)wloss[1] +
                (double)wloss[2] + (double)wloss[3];
    unsigned long long fx = (unsigned long long)(long long)(bl * 4294967296.0);
    atomicAdd(acc, fx);
    __threadfence();
    unsigned int done = atomicAdd(ticket, 1u);
    if (done == (unsigned int)(gridDim.x - 1)) {
      unsigned long long total = atomicAdd(acc, 0ull);   // atomic read
      out[0] = (float)((double)total * (1.0 / 4294967296.0) / (double)NB);
    }
  }
}

extern "C" void kernel_launch(void* const* d_in, const int* in_sizes, int n_in,
                              void* d_out, int out_size, void* d_ws, size_t ws_size,
                              hipStream_t stream) {
  const float* x = (const float*)d_in[0];          // [B, C, T] f32
  const int* y = (const int*)d_in[1];              // [B*L] i32
  const int* lens = (const int*)d_in[2];           // [B] i32
  float* out = (float*)d_out;                      // scalar f32

  int* prefix = (int*)d_ws;
  unsigned long long* acc = (unsigned long long*)((char*)d_ws + NB * sizeof(int));
  unsigned int* ticket = (unsigned int*)((char*)d_ws + NB * sizeof(int) + 8);

  prefix_kernel<<<1, 256, 0, stream>>>(lens, prefix, acc, ticket);
  ace_kernel<<<GRID, 256, 0, stream>>>(x, y, lens, prefix, acc, ticket, out);
}

// Round 3
// 110.177 us; speedup vs baseline: 1.0476x; 1.0476x over previous
//
#include <hip/hip_runtime.h>
#include <float.h>
#include <math.h>

#define NB 8192      // batch
#define NC 128       // classes
#define NT 64        // time steps
#define ACE_EPS 1e-5f
#define GRID (NB / 4)

// workspace layout:
//   [0, NB*4)            prefix[NB]  (int)
//   [NB*4, NB*4+8)       acc         (unsigned long long, fixed-point 2^32 loss sum)
//   [NB*4+8, NB*4+12)    ticket      (unsigned int)

// ---------------------------------------------------------------------------
// 1) exclusive prefix sum of target_lengths + zero the accumulator/ticket.
// ---------------------------------------------------------------------------
__global__ __launch_bounds__(256) void prefix_kernel(
    const int* __restrict__ lens, int* __restrict__ prefix,
    unsigned long long* __restrict__ acc, unsigned int* __restrict__ ticket) {
  if (threadIdx.x == 0) { *acc = 0ull; *ticket = 0u; }
  const int tid = threadIdx.x;
  const int lane = tid & 63;
  const int wid = tid >> 6;

  int4 v[8];
  const int4* l4 = (const int4*)lens + tid * 8;   // 32 ints per thread
#pragma unroll
  for (int i = 0; i < 8; ++i) v[i] = l4[i];
  int s = 0;
#pragma unroll
  for (int i = 0; i < 8; ++i) s += v[i].x + v[i].y + v[i].z + v[i].w;

  int scan = s;
#pragma unroll
  for (int off = 1; off < 64; off <<= 1) {
    int t = __shfl_up(scan, off, 64);
    if (lane >= off) scan += t;
  }
  __shared__ int wsum[4];
  if (lane == 63) wsum[wid] = scan;
  __syncthreads();
  int wbase = 0;
  for (int w = 0; w < wid; ++w) wbase += wsum[w];

  int run = wbase + scan - s;
  int4 o[8];
#pragma unroll
  for (int i = 0; i < 8; ++i) {
    const int a = run;
    const int b2 = a + v[i].x;
    const int c2 = b2 + v[i].y;
    const int d2 = c2 + v[i].z;
    o[i] = make_int4(a, b2, c2, d2);
    run = d2 + v[i].w;
  }
  int4* p4 = (int4*)prefix + tid * 8;
#pragma unroll
  for (int i = 0; i < 8; ++i) p4[i] = o[i];
}

// ---------------------------------------------------------------------------
// 2) fused per-sample ACE loss + deterministic global mean.
//    One wave per sample, 4 samples per 256-thread block.
//    Lane mapping: tg = lane&15 covers t = 4*tg..4*tg+3 (float4 load),
//                  crow = lane>>4 covers c = 4*cc + crow.
//    KEY CHANGE (R3): issue ALL 32 float4 loads up front into registers
//    (fully unrolled, static indices) -> up to 32 loads in flight per wave
//    to cover L2/L3/HBM latency; compare chain consumes under decreasing
//    vmcnt. No min-waves clamp: let the compiler take ~200 VGPRs.
// ---------------------------------------------------------------------------
__global__ __launch_bounds__(256) void ace_kernel(
    const float* __restrict__ x, const int* __restrict__ y,
    const int* __restrict__ lens, const int* __restrict__ prefix,
    unsigned long long* __restrict__ acc, unsigned int* __restrict__ ticket,
    float* __restrict__ out) {
  const int wave = threadIdx.x >> 6;
  const int lane = threadIdx.x & 63;
  const int b = blockIdx.x * 4 + wave;
  const int crow = lane >> 4;
  const int tg = lane & 15;

  __shared__ int nk[4][NC];
  __shared__ int yk[4][NC];
  __shared__ float wloss[4];
  // per-wave rows only -> wave-internal ordering suffices, no block sync
  nk[wave][lane] = 0; nk[wave][lane + 64] = 0;
  yk[wave][lane] = 0; yk[wave][lane + 64] = 0;

  // ---- issue the entire 32 KB sample tile as 32 in-flight float4 loads ----
  const float4* xv = (const float4*)(x + (size_t)b * (NC * NT));
  float4 v[32];
#pragma unroll
  for (int i = 0; i < 32; ++i) v[i] = xv[i * 64 + lane];

  // ---- streaming argmax over C for each t (consumes loads in order) ----
  float mv[4];
  int am[4];
#pragma unroll
  for (int j = 0; j < 4; ++j) { mv[j] = -FLT_MAX; am[j] = 0; }

#pragma unroll
  for (int i = 0; i < 32; ++i) {
    const int c = i * 4 + crow;
    float vv[4] = {v[i].x, v[i].y, v[i].z, v[i].w};
#pragma unroll
    for (int j = 0; j < 4; ++j) {
      if (vv[j] > mv[j]) { mv[j] = vv[j]; am[j] = c; }   // strict > : first max
    }
  }

  // combine across the 4 lanes (crow dim) sharing one t-group; min idx on tie
#pragma unroll
  for (int j = 0; j < 4; ++j) {
#pragma unroll
    for (int off = 16; off < 64; off <<= 1) {
      float om = __shfl_xor(mv[j], off, 64);
      int oa = __shfl_xor(am[j], off, 64);
      if (om > mv[j] || (om == mv[j] && oa < am[j])) { mv[j] = om; am[j] = oa; }
    }
  }

  // lane records argmax for t = 4*tg + crow (static-index select chain)
  int my_am = am[0];
  if (crow == 1) my_am = am[1];
  if (crow == 2) my_am = am[2];
  if (crow == 3) my_am = am[3];
  atomicAdd(&nk[wave][my_am], 1);

  // ---- target histogram (small dependent chain; hides under other waves) ----
  const int len = lens[b];
  const int start = prefix[b];
  for (int i = lane; i < len; i += 64) atomicAdd(&yk[wave][y[start + i]], 1);

  // ---- per-sample masked loss (classes lane, lane+64) ----
  const int yk0 = yk[wave][lane], yk1 = yk[wave][lane + 64];
  const int nk0 = yk0 ? nk[wave][lane] : 0;
  const int nk1 = yk1 ? nk[wave][lane + 64] : 0;
  int ns = nk0 + nk1;
  int ys = yk0 + yk1;
#pragma unroll
  for (int off = 1; off < 64; off <<= 1) {
    ns += __shfl_xor(ns, off, 64);
    ys += __shfl_xor(ys, off, 64);
  }
  const float inv_ns = (ns > 0) ? (1.0f / (float)ns) : 0.0f;
  const float inv_ys = (ys > 0) ? (1.0f / (float)ys) : 0.0f;
  float a = 0.0f;
  if (yk0) {
    float np = (ns == 0) ? ACE_EPS : fmaxf((float)nk0 * inv_ns, ACE_EPS);
    a -= np * logf((float)yk0 * inv_ys);
  }
  if (yk1) {
    float np = (ns == 0) ? ACE_EPS : fmaxf((float)nk1 * inv_ns, ACE_EPS);
    a -= np * logf((float)yk1 * inv_ys);
  }
#pragma unroll
  for (int off = 1; off < 64; off <<= 1) a += __shfl_xor(a, off, 64);
  if (lane == 0) wloss[wave] = a;

  // ---- deterministic fused mean (fixed-point u64 atomic + ticket) ----
  __syncthreads();
  if (threadIdx.x == 0) {
    double bl = (double)wloss[0] + (double)wloss[1] +
                (double)wloss[2] + (double)wloss[3];
    unsigned long long fx = (unsigned long long)(long long)(bl * 4294967296.0);
    atomicAdd(acc, fx);
    __threadfence();
    unsigned int done = atomicAdd(ticket, 1u);
    if (done == (unsigned int)(gridDim.x - 1)) {
      unsigned long long total = atomicAdd(acc, 0ull);   // atomic read
      out[0] = (float)((double)total * (1.0 / 4294967296.0) / (double)NB);
    }
  }
}

extern "C" void kernel_launch(void* const* d_in, const int* in_sizes, int n_in,
                              void* d_out, int out_size, void* d_ws, size_t ws_size,
                              hipStream_t stream) {
  const float* x = (const float*)d_in[0];          // [B, C, T] f32
  const int* y = (const int*)d_in[1];              // [B*L] i32
  const int* lens = (const int*)d_in[2];           // [B] i32
  float* out = (float*)d_out;                      // scalar f32

  int* prefix = (int*)d_ws;
  unsigned long long* acc = (unsigned long long*)((char*)d_ws + NB * sizeof(int));
  unsigned int* ticket = (unsigned int*)((char*)d_ws + NB * sizeof(int) + 8);

  prefix_kernel<<<1, 256, 0, stream>>>(lens, prefix, acc, ticket);
  ace_kernel<<<GRID, 256, 0, stream>>>(x, y, lens, prefix, acc, ticket, out);
}

// Round 4
// 62.061 us; speedup vs baseline: 1.8598x; 1.7753x over previous
//
#include <hip/hip_runtime.h>
#include <float.h>
#include <math.h>

#define NB 8192      // batch
#define NC 128       // classes
#define NT 64        // time steps
#define ACE_EPS 1e-5f

// workspace layout:
//   [0,      32KB)   prefix[NB]   (int)
//   [32KB,   64KB)   loss[NB]     (float)
//   [64KB,  576KB)   predicts[NB*NT] (u8)

// ---------------------------------------------------------------------------
// 0) exclusive prefix sum of target_lengths — single block, 256 thr, ~3 us
// ---------------------------------------------------------------------------
__global__ __launch_bounds__(256) void prefix_kernel(
    const int* __restrict__ lens, int* __restrict__ prefix) {
  const int tid = threadIdx.x;
  const int lane = tid & 63;
  const int wid = tid >> 6;

  int4 v[8];
  const int4* l4 = (const int4*)lens + tid * 8;   // 32 ints per thread
#pragma unroll
  for (int i = 0; i < 8; ++i) v[i] = l4[i];
  int s = 0;
#pragma unroll
  for (int i = 0; i < 8; ++i) s += v[i].x + v[i].y + v[i].z + v[i].w;

  int scan = s;
#pragma unroll
  for (int off = 1; off < 64; off <<= 1) {
    int t = __shfl_up(scan, off, 64);
    if (lane >= off) scan += t;
  }
  __shared__ int wsum[4];
  if (lane == 63) wsum[wid] = scan;
  __syncthreads();
  int wbase = 0;
  for (int w = 0; w < wid; ++w) wbase += wsum[w];

  int run = wbase + scan - s;
  int4 o[8];
#pragma unroll
  for (int i = 0; i < 8; ++i) {
    const int a = run;
    const int b2 = a + v[i].x;
    const int c2 = b2 + v[i].y;
    const int d2 = c2 + v[i].z;
    o[i] = make_int4(a, b2, c2, d2);
    run = d2 + v[i].w;
  }
  int4* p4 = (int4*)prefix + tid * 8;
#pragma unroll
  for (int i = 0; i < 8; ++i) p4[i] = o[i];
}

// ---------------------------------------------------------------------------
// A) pure-streaming argmax over C. One wave per sample; NO LDS, NO atomics,
//    no y-chain — copy-shaped. Lane mapping: tg=lane&15 (t=4tg..4tg+3),
//    crow=lane>>4 (c = 4*cc+crow). Wave reads 1 KiB contiguous per iter.
//    launch_bounds(256,8): VGPR<=64 -> 8 waves/SIMD; unroll-8 pipeline fits.
// ---------------------------------------------------------------------------
__global__ __launch_bounds__(256, 8) void argmax_kernel(
    const float* __restrict__ x, unsigned char* __restrict__ preds) {
  const int wave = threadIdx.x >> 6;
  const int lane = threadIdx.x & 63;
  const int b = blockIdx.x * 4 + wave;
  const int crow = lane >> 4;
  const int tg = lane & 15;

  const float4* xv = (const float4*)(x + (size_t)b * (NC * NT));

  float mv[4];
  int am[4];
#pragma unroll
  for (int j = 0; j < 4; ++j) { mv[j] = -FLT_MAX; am[j] = 0; }

#pragma unroll 8
  for (int cc = 0; cc < 32; ++cc) {
    const int c = cc * 4 + crow;
    float4 v = xv[cc * 64 + lane];
    float vv[4] = {v.x, v.y, v.z, v.w};
#pragma unroll
    for (int j = 0; j < 4; ++j) {
      if (vv[j] > mv[j]) { mv[j] = vv[j]; am[j] = c; }   // strict > : first max
    }
  }

  // combine across the 4 lanes (crow dim) sharing one t-group; min idx on tie
#pragma unroll
  for (int j = 0; j < 4; ++j) {
#pragma unroll
    for (int off = 16; off < 64; off <<= 1) {
      float om = __shfl_xor(mv[j], off, 64);
      int oa = __shfl_xor(am[j], off, 64);
      if (om > mv[j] || (om == mv[j] && oa < am[j])) { mv[j] = om; am[j] = oa; }
    }
  }

  int my_am = am[0];
  if (crow == 1) my_am = am[1];
  if (crow == 2) my_am = am[2];
  if (crow == 3) my_am = am[3];
  // one 64B line per wave (intra-line permutation coalesces)
  preds[b * NT + 4 * tg + crow] = (unsigned char)my_am;
}

// ---------------------------------------------------------------------------
// B) per-sample loss, LDS-free via ballot/popcount. One wave per sample.
//    Lane t=lane holds its pred; lanes<len hold their y target. For each
//    target i: broadcast class c, nk[c]=popc(ballot(pred==c)),
//    yk[c]=popc(ballot(y==c)), "owner" = first occurrence of c (dedup).
//    All quantities wave-uniform -> no reductions needed.
// ---------------------------------------------------------------------------
__global__ __launch_bounds__(256) void loss_kernel(
    const unsigned char* __restrict__ preds, const int* __restrict__ y,
    const int* __restrict__ lens, const int* __restrict__ prefix,
    float* __restrict__ loss_out) {
  const int wave = threadIdx.x >> 6;
  const int lane = threadIdx.x & 63;
  const int b = blockIdx.x * 4 + wave;

  const int len = lens[b];
  const int start = prefix[b];
  const int my_pred = preds[b * NT + lane];
  const int yv = (lane < len) ? y[start + lane] : -1;

  // pass 1: n_sum over distinct target classes
  int ns = 0;
  for (int i = 0; i < len; ++i) {
    const int c = __shfl(yv, i, 64);
    const unsigned long long baly = __ballot(lane < len && yv == c);
    const int nkc = __popcll(__ballot(my_pred == c));
    if ((int)__ffsll(baly) - 1 == i) ns += nkc;   // uniform: first occurrence
  }

  const float inv_ns = (ns > 0) ? (1.0f / (float)ns) : 0.0f;
  const float inv_ys = 1.0f / (float)len;         // y_sum == len
  float a = 0.0f;
  for (int i = 0; i < len; ++i) {
    const int c = __shfl(yv, i, 64);
    const unsigned long long baly = __ballot(lane < len && yv == c);
    if ((int)__ffsll(baly) - 1 == i) {            // uniform branch
      const int nkc = __popcll(__ballot(my_pred == c));
      const int ykc = __popcll(baly);
      const float np = (ns == 0) ? ACE_EPS : fmaxf((float)nkc * inv_ns, ACE_EPS);
      a -= np * logf((float)ykc * inv_ys);
    }
  }
  if (lane == 0) loss_out[b] = a;
}

// ---------------------------------------------------------------------------
// C) deterministic mean over B per-sample losses — single 1024-thread block
// ---------------------------------------------------------------------------
__global__ void reduce_kernel(const float* __restrict__ loss,
                              float* __restrict__ out) {
  __shared__ float s[1024];
  float a = 0.0f;
  for (int i = threadIdx.x; i < NB; i += 1024) a += loss[i];
  s[threadIdx.x] = a;
  __syncthreads();
  for (int off = 512; off > 0; off >>= 1) {
    if ((int)threadIdx.x < off) s[threadIdx.x] += s[threadIdx.x + off];
    __syncthreads();
  }
  if (threadIdx.x == 0) out[0] = s[0] / (float)NB;
}

extern "C" void kernel_launch(void* const* d_in, const int* in_sizes, int n_in,
                              void* d_out, int out_size, void* d_ws, size_t ws_size,
                              hipStream_t stream) {
  const float* x = (const float*)d_in[0];          // [B, C, T] f32
  const int* y = (const int*)d_in[1];              // [B*L] i32
  const int* lens = (const int*)d_in[2];           // [B] i32
  float* out = (float*)d_out;                      // scalar f32

  int* prefix = (int*)d_ws;                                      // 32 KB
  float* loss = (float*)((char*)d_ws + 32 * 1024);               // 32 KB
  unsigned char* preds = (unsigned char*)d_ws + 64 * 1024;       // 512 KB

  prefix_kernel<<<1, 256, 0, stream>>>(lens, prefix);
  argmax_kernel<<<NB / 4, 256, 0, stream>>>(x, preds);
  loss_kernel<<<NB / 4, 256, 0, stream>>>(preds, y, lens, prefix, loss);
  reduce_kernel<<<1, 1024, 0, stream>>>(loss, out);
}

// Round 5
// 58.103 us; speedup vs baseline: 1.9865x; 1.0681x over previous
//
#include <hip/hip_runtime.h>
#include <float.h>
#include <math.h>

#define NB 8192      // batch
#define NC 128       // classes
#define NT 64        // time steps
#define ACE_EPS 1e-5f

// workspace layout:
//   [0,      32KB)   prefix[NB]   (int)
//   [32KB,   64KB)   loss[NB]     (float)

// ---------------------------------------------------------------------------
// 0) exclusive prefix sum of target_lengths — single block, 256 thr, ~3 us
// ---------------------------------------------------------------------------
__global__ __launch_bounds__(256) void prefix_kernel(
    const int* __restrict__ lens, int* __restrict__ prefix) {
  const int tid = threadIdx.x;
  const int lane = tid & 63;
  const int wid = tid >> 6;

  int4 v[8];
  const int4* l4 = (const int4*)lens + tid * 8;   // 32 ints per thread
#pragma unroll
  for (int i = 0; i < 8; ++i) v[i] = l4[i];
  int s = 0;
#pragma unroll
  for (int i = 0; i < 8; ++i) s += v[i].x + v[i].y + v[i].z + v[i].w;

  int scan = s;
#pragma unroll
  for (int off = 1; off < 64; off <<= 1) {
    int t = __shfl_up(scan, off, 64);
    if (lane >= off) scan += t;
  }
  __shared__ int wsum[4];
  if (lane == 63) wsum[wid] = scan;
  __syncthreads();
  int wbase = 0;
  for (int w = 0; w < wid; ++w) wbase += wsum[w];

  int run = wbase + scan - s;
  int4 o[8];
#pragma unroll
  for (int i = 0; i < 8; ++i) {
    const int a = run;
    const int b2 = a + v[i].x;
    const int c2 = b2 + v[i].y;
    const int d2 = c2 + v[i].z;
    o[i] = make_int4(a, b2, c2, d2);
    run = d2 + v[i].w;
  }
  int4* p4 = (int4*)prefix + tid * 8;
#pragma unroll
  for (int i = 0; i < 8; ++i) p4[i] = o[i];
}

// ---------------------------------------------------------------------------
// A) fused streaming argmax + per-sample ACE loss. One wave per sample,
//    4 samples per 256-thread block. NO LDS, NO atomics, no cross-wave deps.
//    Lane mapping: tg=lane&15 (t=4tg..4tg+3), crow=lane>>4 (c=4*cc+crow);
//    wave reads 1 KiB contiguous per iter (float4/lane).
//    After the shuffle-combine, lane l holds the argmax of t = 4*(l&15)+(l>>4)
//    — a BIJECTION over t — so nk[c] = popc(ballot(my_am==c)) directly.
//    Loss tail is ~16 ballots for len=8: register-only, no preds round-trip.
// ---------------------------------------------------------------------------
__global__ __launch_bounds__(256, 8) void ace_fused_kernel(
    const float* __restrict__ x, const int* __restrict__ y,
    const int* __restrict__ lens, const int* __restrict__ prefix,
    float* __restrict__ loss_out) {
  const int wave = threadIdx.x >> 6;
  const int lane = threadIdx.x & 63;
  const int b = blockIdx.x * 4 + wave;
  const int crow = lane >> 4;

  const float4* xv = (const float4*)(x + (size_t)b * (NC * NT));

  float mv[4];
  int am[4];
#pragma unroll
  for (int j = 0; j < 4; ++j) { mv[j] = -FLT_MAX; am[j] = 0; }

#pragma unroll 8
  for (int cc = 0; cc < 32; ++cc) {
    const int c = cc * 4 + crow;
    float4 v = xv[cc * 64 + lane];
    float vv[4] = {v.x, v.y, v.z, v.w};
#pragma unroll
    for (int j = 0; j < 4; ++j) {
      if (vv[j] > mv[j]) { mv[j] = vv[j]; am[j] = c; }   // strict > : first max
    }
  }

  // combine across the 4 lanes (crow dim) sharing one t-group; min idx on tie
#pragma unroll
  for (int j = 0; j < 4; ++j) {
#pragma unroll
    for (int off = 16; off < 64; off <<= 1) {
      float om = __shfl_xor(mv[j], off, 64);
      int oa = __shfl_xor(am[j], off, 64);
      if (om > mv[j] || (om == mv[j] && oa < am[j])) { mv[j] = om; am[j] = oa; }
    }
  }

  // lane's own argmax for t = 4*tg + crow (static-index select chain)
  int my_am = am[0];
  if (crow == 1) my_am = am[1];
  if (crow == 2) my_am = am[2];
  if (crow == 3) my_am = am[3];

  // ---- loss tail: ballot/popcount, all wave-uniform, no memory traffic
  //      beyond len ints of y (len <= 64; harness L=8) ----
  const int len = lens[b];
  const int start = prefix[b];
  const int yv = (lane < len) ? y[start + lane] : -1;

  // n_sum over distinct target classes
  int ns = 0;
  for (int i = 0; i < len; ++i) {
    const int c = __shfl(yv, i, 64);
    const unsigned long long baly = __ballot(lane < len && yv == c);
    const int nkc = __popcll(__ballot(my_am == c));
    if ((int)__ffsll(baly) - 1 == i) ns += nkc;   // uniform: first occurrence
  }

  const float inv_ns = (ns > 0) ? (1.0f / (float)ns) : 0.0f;
  const float inv_ys = 1.0f / (float)len;         // y_sum == len
  float a = 0.0f;
  for (int i = 0; i < len; ++i) {
    const int c = __shfl(yv, i, 64);
    const unsigned long long baly = __ballot(lane < len && yv == c);
    if ((int)__ffsll(baly) - 1 == i) {            // uniform branch
      const int nkc = __popcll(__ballot(my_am == c));
      const int ykc = __popcll(baly);
      const float np = (ns == 0) ? ACE_EPS : fmaxf((float)nkc * inv_ns, ACE_EPS);
      a -= np * logf((float)ykc * inv_ys);
    }
  }
  if (lane == 0) loss_out[b] = a;
}

// ---------------------------------------------------------------------------
// C) deterministic mean over B per-sample losses — single 1024-thread block
// ---------------------------------------------------------------------------
__global__ void reduce_kernel(const float* __restrict__ loss,
                              float* __restrict__ out) {
  __shared__ float s[1024];
  float a = 0.0f;
  for (int i = threadIdx.x; i < NB; i += 1024) a += loss[i];
  s[threadIdx.x] = a;
  __syncthreads();
  for (int off = 512; off > 0; off >>= 1) {
    if ((int)threadIdx.x < off) s[threadIdx.x] += s[threadIdx.x + off];
    __syncthreads();
  }
  if (threadIdx.x == 0) out[0] = s[0] / (float)NB;
}

extern "C" void kernel_launch(void* const* d_in, const int* in_sizes, int n_in,
                              void* d_out, int out_size, void* d_ws, size_t ws_size,
                              hipStream_t stream) {
  const float* x = (const float*)d_in[0];          // [B, C, T] f32
  const int* y = (const int*)d_in[1];              // [B*L] i32
  const int* lens = (const int*)d_in[2];           // [B] i32
  float* out = (float*)d_out;                      // scalar f32

  int* prefix = (int*)d_ws;                                      // 32 KB
  float* loss = (float*)((char*)d_ws + 32 * 1024);               // 32 KB

  prefix_kernel<<<1, 256, 0, stream>>>(lens, prefix);
  ace_fused_kernel<<<NB / 4, 256, 0, stream>>>(x, y, lens, prefix, loss);
  reduce_kernel<<<1, 1024, 0, stream>>>(loss, out);
}